// Round 3
// baseline (119.305 us; speedup 1.0000x reference)
//
#include <hip/hip_runtime.h>
#include <hip/hip_fp16.h>
#include <math.h>

#define NN 4096
#define KTOP 20
#define EPSF 1e-6f

// ---------------- block sum over 256 threads (4 waves) ----------------
__device__ __forceinline__ float block_rsumf(float v, volatile float* red) {
#pragma unroll
  for (int o = 1; o < 64; o <<= 1) v += __shfl_xor(v, o, 64);
  __syncthreads();
  if ((threadIdx.x & 63) == 0) red[threadIdx.x >> 6] = v;
  __syncthreads();
  return red[0] + red[1] + red[2] + red[3];
}

// ---------------- K1: feat (normalized), sev, impacted count ----------------
__global__ void k_prep(const float* __restrict__ xh, const float* __restrict__ ev,
                       float2* __restrict__ featn, float* __restrict__ sev,
                       int* __restrict__ cnt) {
  int i = blockIdx.x * 256 + threadIdx.x;
  float sx = 0.f, sy = 0.f, se = 0.f;
  const float2* xh2 = (const float2*)xh;
  for (int bt = 0; bt < 192; ++bt) {
    float2 v = xh2[bt * NN + i];
    sx += v.x; sy += v.y;
    se += ev[bt * NN + i];
  }
  sx *= (1.f / 192.f); sy *= (1.f / 192.f); se *= (1.f / 192.f);
  float nrm = sqrtf(sx * sx + sy * sy) + EPSF;
  featn[i] = make_float2(sx / nrm, sy / nrm);
  sev[i] = se;
  unsigned long long m = __ballot(se > 0.f);
  if ((threadIdx.x & 63) == 0) atomicAdd(cnt, (int)__popcll(m));
}

// ---------------- block-wide exact fallback select (rare) ----------------
__device__ __forceinline__ void fb_row(
    int i, const float (&v)[16], int* kidx, float* kval, float* dinv,
    volatile float* redf, volatile int* redi, int* eq_js, int* eq_cnt, int* slot) {
  const int tid = threadIdx.x;
  const int lane = tid & 63, wv = tid >> 6;
  unsigned cur = 0;
  for (int bit = 30; bit >= 0; --bit) {
    float tf = __uint_as_float(cur | (1u << bit));
    int lc = 0;
#pragma unroll
    for (int c = 0; c < 16; ++c) lc += (v[c] >= tf) ? 1 : 0;
#pragma unroll
    for (int o = 1; o < 64; o <<= 1) lc += __shfl_xor(lc, o, 64);
    __syncthreads();
    if (lane == 0) redi[wv] = lc;
    __syncthreads();
    int tot = redi[0] + redi[1] + redi[2] + redi[3];
    if (tot >= KTOP) cur |= (1u << bit);
  }
  float T = __uint_as_float(cur);
  int lgt = 0;
#pragma unroll
  for (int c = 0; c < 16; ++c) lgt += (v[c] > T) ? 1 : 0;
#pragma unroll
  for (int o = 1; o < 64; o <<= 1) lgt += __shfl_xor(lgt, o, 64);
  __syncthreads();
  if (lane == 0) redi[wv] = lgt;
  if (tid == 0) *eq_cnt = 0;
  __syncthreads();
  int cgt = redi[0] + redi[1] + redi[2] + redi[3];

  float lsum = 0.f;
#pragma unroll
  for (int c = 0; c < 16; ++c) {
    if (v[c] > T) {
      int p = atomicAdd(slot, 1);
      kidx[i * KTOP + p] = c * 256 + tid;
      kval[i * KTOP + p] = v[c];
      lsum += v[c];
    } else if (v[c] == T) {
      int p = atomicAdd(eq_cnt, 1);
      if (p < 64) eq_js[p] = c * 256 + tid;
    }
  }
  __syncthreads();
  int need = KTOP - cgt;
  if (tid == 0) {
    int m = *eq_cnt < 64 ? *eq_cnt : 64;
    for (int s = 0; s < need; ++s) {
      int best = s;
      for (int u = s + 1; u < m; ++u)
        if (eq_js[u] < eq_js[best]) best = u;
      int tmp = eq_js[s]; eq_js[s] = eq_js[best]; eq_js[best] = tmp;
      kidx[i * KTOP + cgt + s] = eq_js[s];
      kval[i * KTOP + cgt + s] = T;
    }
  }
  float tot = block_rsumf(lsum, redf);
  if (tid == 0) dinv[i] = 1.f / sqrtf(tot + (float)need * T + 1.f + EPSF);
}

// ---------------- K2: 2 rows/block, fused A_dyn + exact top-k ----------------
__global__ __launch_bounds__(256) void k_row(
    const float* __restrict__ base_adj, const float2* __restrict__ featn,
    const float* __restrict__ sev, const float* __restrict__ nv1,
    const float* __restrict__ nv2, const float* __restrict__ alpha,
    const int* __restrict__ cnt, int* __restrict__ kidx,
    float* __restrict__ kval, float* __restrict__ dinv) {
  const int i0 = blockIdx.x * 2;
  const int tid = threadIdx.x;
  const int lane = tid & 63, wv = tid >> 6;

  __shared__ float maxima[2][256];
  __shared__ float candV[2][64];
  __shared__ int candJ[2][64];
  __shared__ float redf[24];
  __shared__ int redi[4];
  __shared__ int ccnt[2], wslot[2];
  __shared__ float sT[2];
  __shared__ int eq_js[64];
  __shared__ int eq_cnt;

  // ---- row constants ----
  float2 fi0 = featn[i0], fi1 = featn[i0 + 1];
  float esc0 = sev[i0] * 0.6065306597f;
  float esc1 = sev[i0 + 1] * 0.6065306597f;
  float v1a[10], v1b[10];
#pragma unroll
  for (int d = 0; d < 10; ++d) {
    v1a[d] = nv1[i0 * 10 + d];
    v1b[d] = nv1[(i0 + 1) * 10 + d];
  }
  float gamma = 1.f / (1.f + __expf(-alpha[0]));

  // ---- pass 1: loads + sums ----
  float b0[16], b1[16], ae0[16], ae1[16];
  __half2 hh0[8], hh1[8];
  float hs0 = 0.f, hs1 = 0.f, as0 = 0.f, as1 = 0.f, ed0 = 0.f, ed1 = 0.f;
  float hp0 = 0.f, hp1 = 0.f;

#pragma unroll
  for (int c = 0; c < 16; ++c) {
    int j = c * 256 + tid;
    float2 fj = featn[j];
    float a0 = 0.f, a1 = 0.f;
#pragma unroll
    for (int d = 0; d < 10; ++d) {
      float w = nv2[d * NN + j];
      a0 += v1a[d] * w;
      a1 += v1b[d] * w;
    }
    float he0 = __expf(fmaxf(fi0.x * fj.x + fi0.y * fj.y, 0.f));
    float he1 = __expf(fmaxf(fi1.x * fj.x + fi1.y * fj.y, 0.f));
    hs0 += he0; hs1 += he1;
    float e0 = __expf(fmaxf(a0, 0.f)), e1 = __expf(fmaxf(a1, 0.f));
    ae0[c] = e0; ae1[c] = e1; as0 += e0; as1 += e1;
    float bb0 = base_adj[(size_t)i0 * NN + j];
    float bb1 = base_adj[(size_t)(i0 + 1) * NN + j];
    b0[c] = bb0; b1[c] = bb1;
    if (esc0 > 0.f) { if (bb0 > 0.f) ed0 += __expf(esc0 * bb0) - 1.f; }
    if (esc1 > 0.f) { if (bb1 > 0.f) ed1 += __expf(esc1 * bb1) - 1.f; }
    if (c & 1) {
      hh0[c >> 1] = __floats2half2_rn(hp0, he0);
      hh1[c >> 1] = __floats2half2_rn(hp1, he1);
    } else { hp0 = he0; hp1 = he1; }
  }

  // ---- fused 6-sum block reduction ----
#pragma unroll
  for (int o = 1; o < 64; o <<= 1) {
    hs0 += __shfl_xor(hs0, o, 64); hs1 += __shfl_xor(hs1, o, 64);
    as0 += __shfl_xor(as0, o, 64); as1 += __shfl_xor(as1, o, 64);
    ed0 += __shfl_xor(ed0, o, 64); ed1 += __shfl_xor(ed1, o, 64);
  }
  if (lane == 0) {
    redf[wv * 6 + 0] = hs0; redf[wv * 6 + 1] = hs1;
    redf[wv * 6 + 2] = as0; redf[wv * 6 + 3] = as1;
    redf[wv * 6 + 4] = ed0; redf[wv * 6 + 5] = ed1;
  }
  __syncthreads();
  float HS0 = redf[0] + redf[6] + redf[12] + redf[18];
  float HS1 = redf[1] + redf[7] + redf[13] + redf[19];
  float AS0 = redf[2] + redf[8] + redf[14] + redf[20];
  float AS1 = redf[3] + redf[9] + redf[15] + redf[21];
  float ES0 = 4096.f + redf[4] + redf[10] + redf[16] + redf[22];
  float ES1 = 4096.f + redf[5] + redf[11] + redf[17] + redf[23];

  float eflag = (*cnt > 0) ? 1.f : 0.f;
  float wh0 = 0.5f * gamma / HS0, wh1 = 0.5f * gamma / HS1;
  float we0 = 0.5f * (1.f - gamma) * eflag / ES0, we1 = 0.5f * (1.f - gamma) * eflag / ES1;
  float wa0 = 0.5f / AS0, wa1 = 0.5f / AS1;

  // ---- pass 2: v values + thread max ----
  float v0[16], v1v[16];
  float m0 = 0.f, m1 = 0.f;
#pragma unroll
  for (int c = 0; c < 16; ++c) {
    float2 hu0 = __half22float2(hh0[c >> 1]);
    float2 hu1 = __half22float2(hh1[c >> 1]);
    float he0 = (c & 1) ? hu0.y : hu0.x;
    float he1 = (c & 1) ? hu1.y : hu1.x;
    float val0 = wh0 * he0 + wa0 * ae0[c] + we0;
    float val1 = wh1 * he1 + wa1 * ae1[c] + we1;
    if (b0[c] > 0.f) {
      float add = 0.5f * b0[c];
      if (esc0 > 0.f) add += we0 * (__expf(esc0 * b0[c]) - 1.f);
      val0 += add;
    }
    if (b1[c] > 0.f) {
      float add = 0.5f * b1[c];
      if (esc1 > 0.f) add += we1 * (__expf(esc1 * b1[c]) - 1.f);
      val1 += add;
    }
    v0[c] = val0; v1v[c] = val1;
    m0 = fmaxf(m0, val0); m1 = fmaxf(m1, val1);
  }
  maxima[0][tid] = m0;
  maxima[1][tid] = m1;
  if (tid < 2) { ccnt[tid] = 0; wslot[tid] = 0; }
  __syncthreads();

  // ---- threshold T per row from 256 thread-maxima (12-bit prefix search) ----
  if (wv < 2) {
    float x0 = maxima[wv][lane], x1 = maxima[wv][lane + 64];
    float x2 = maxima[wv][lane + 128], x3 = maxima[wv][lane + 192];
    unsigned cur = 0;
    for (int bit = 30; bit >= 19; --bit) {
      float tf = __uint_as_float(cur | (1u << bit));
      int c_ = __popcll(__ballot(x0 >= tf)) + __popcll(__ballot(x1 >= tf)) +
               __popcll(__ballot(x2 >= tf)) + __popcll(__ballot(x3 >= tf));
      if (c_ >= KTOP) cur |= (1u << bit);
    }
    sT[wv] = __uint_as_float(cur);
  }
  __syncthreads();
  float T0 = sT[0], T1 = sT[1];

  // ---- collect candidates ----
#pragma unroll
  for (int c = 0; c < 16; ++c) {
    if (v0[c] >= T0) {
      int p = atomicAdd(&ccnt[0], 1);
      if (p < 64) { candV[0][p] = v0[c]; candJ[0][p] = c * 256 + tid; }
    }
    if (v1v[c] >= T1) {
      int p = atomicAdd(&ccnt[1], 1);
      if (p < 64) { candV[1][p] = v1v[c]; candJ[1][p] = c * 256 + tid; }
    }
  }
  __syncthreads();
  int fb = ((ccnt[0] > 64) ? 1 : 0) | ((ccnt[1] > 64) ? 2 : 0);

  // ---- wave-local exact top-20 among candidates ----
  if (wv < 2 && !(fb & (1 << wv))) {
    int r = wv, n = ccnt[r];
    float lv = (lane < n) ? candV[r][lane] : 0.f;
    int lj = (lane < n) ? candJ[r][lane] : 0x7FFFFFFF;
    unsigned cur = 0;
    for (int bit = 30; bit >= 0; --bit) {
      float tf = __uint_as_float(cur | (1u << bit));
      if (__popcll(__ballot(lv >= tf)) >= KTOP) cur |= (1u << bit);
    }
    float T = __uint_as_float(cur);
    bool gt = lv > T;
    int cgt = __popcll(__ballot(gt));
    if (gt) {
      int p = atomicAdd(&wslot[r], 1);
      kidx[(i0 + r) * KTOP + p] = lj;
      kval[(i0 + r) * KTOP + p] = lv;
    }
    int need = KTOP - cgt;
    bool eq = (lv == T);
    for (int k = 0; k < need; ++k) {
      int pj = eq ? lj : 0x7FFFFFFF;
#pragma unroll
      for (int o = 1; o < 64; o <<= 1) {
        int q = __shfl_xor(pj, o, 64);
        pj = q < pj ? q : pj;
      }
      if (lane == 0) {
        kidx[(i0 + r) * KTOP + cgt + k] = pj;
        kval[(i0 + r) * KTOP + cgt + k] = T;
      }
      if (lj == pj) eq = false;
    }
    float ds = gt ? lv : 0.f;
#pragma unroll
    for (int o = 1; o < 64; o <<= 1) ds += __shfl_xor(ds, o, 64);
    if (lane == 0) {
      float deg = ds + (float)need * T + 1.f;
      dinv[i0 + r] = 1.f / sqrtf(deg + EPSF);
    }
  }

  // ---- rare fallback: block-wide exact select ----
  if (fb) {
    __syncthreads();
    if (fb & 1) fb_row(i0, v0, kidx, kval, dinv, redf, redi, eq_js, &eq_cnt, &wslot[0]);
    if (fb & 2) fb_row(i0 + 1, v1v, kidx, kval, dinv, redf, redi, eq_js, &eq_cnt, &wslot[1]);
  }
}

// ---------------- K3: write normalized sparse output ----------------
__global__ __launch_bounds__(256) void k_write(
    const int* __restrict__ kidx, const float* __restrict__ kval,
    const float* __restrict__ dinv, float* __restrict__ out) {
  const int i = blockIdx.x;
  const int tid = threadIdx.x;
  __shared__ float row[NN];
  float4* r4 = (float4*)row;
#pragma unroll
  for (int c = 0; c < 4; ++c) r4[c * 256 + tid] = make_float4(0.f, 0.f, 0.f, 0.f);
  __syncthreads();
  if (tid < KTOP) {
    int j = kidx[i * KTOP + tid];
    row[j] = kval[i * KTOP + tid];
  }
  __syncthreads();
  float di = dinv[i];
  const float4* dv4 = (const float4*)dinv;
  float4* o4 = (float4*)out;
#pragma unroll
  for (int c = 0; c < 4; ++c) {
    int j4 = c * 256 + tid;
    float4 rv = r4[j4];
    float4 dv = dv4[j4];
    int jb = j4 * 4;
    float4 o;
    o.x = di * (rv.x + ((jb + 0) == i ? 1.f : 0.f)) * dv.x;
    o.y = di * (rv.y + ((jb + 1) == i ? 1.f : 0.f)) * dv.y;
    o.z = di * (rv.z + ((jb + 2) == i ? 1.f : 0.f)) * dv.z;
    o.w = di * (rv.w + ((jb + 3) == i ? 1.f : 0.f)) * dv.w;
    o4[(size_t)i * (NN / 4) + j4] = o;
  }
}

extern "C" void kernel_launch(void* const* d_in, const int* in_sizes, int n_in,
                              void* d_out, int out_size, void* d_ws, size_t ws_size,
                              hipStream_t stream) {
  const float* xh    = (const float*)d_in[0];
  const float* ev    = (const float*)d_in[1];
  const float* base  = (const float*)d_in[2];
  const float* nv1   = (const float*)d_in[3];
  const float* nv2   = (const float*)d_in[4];
  const float* alpha = (const float*)d_in[5];
  float* out = (float*)d_out;

  char* ws = (char*)d_ws;
  int*    cnt   = (int*)ws;                       // 4 B (pad 256)
  float2* featn = (float2*)(ws + 256);            // 32 KB
  float*  sev   = (float*)(ws + 33024);           // 16 KB
  float*  dinv  = (float*)(ws + 49408);           // 16 KB
  int*    kidx  = (int*)(ws + 65792);             // 320 KB
  float*  kval  = (float*)(ws + 393472);          // 320 KB

  hipMemsetAsync(cnt, 0, 4, stream);
  k_prep<<<NN / 256, 256, 0, stream>>>(xh, ev, featn, sev, cnt);
  k_row<<<NN / 2, 256, 0, stream>>>(base, featn, sev, nv1, nv2, alpha, cnt, kidx, kval, dinv);
  k_write<<<NN, 256, 0, stream>>>(kidx, kval, dinv, out);
}

// Round 4
// 85.635 us; speedup vs baseline: 1.3932x; 1.3932x over previous
//
#include <hip/hip_runtime.h>
#include <math.h>

#define NN 4096
#define KTOP 20
#define EPSF 1e-6f

// ---------------- block sum over 256 threads (4 waves) ----------------
__device__ __forceinline__ float block_rsumf(float v, volatile float* red) {
#pragma unroll
  for (int o = 1; o < 64; o <<= 1) v += __shfl_xor(v, o, 64);
  __syncthreads();
  if ((threadIdx.x & 63) == 0) red[threadIdx.x >> 6] = v;
  __syncthreads();
  return red[0] + red[1] + red[2] + red[3];
}

// ---------------- K0a: partial sums over bt chunks (deterministic, no atomics) ----------------
__global__ __launch_bounds__(256) void k_prep_a(const float* __restrict__ xh,
    const float* __restrict__ ev, float* __restrict__ psx,
    float* __restrict__ psy, float* __restrict__ pse) {
  int ic = blockIdx.x & 15, tc = blockIdx.x >> 4;
  int i = ic * 256 + threadIdx.x;
  const float2* xh2 = (const float2*)xh;
  float sx = 0.f, sy = 0.f, se = 0.f;
  for (int bt = tc * 24; bt < tc * 24 + 24; ++bt) {
    float2 v = xh2[(size_t)bt * NN + i];
    sx += v.x; sy += v.y;
    se += ev[(size_t)bt * NN + i];
  }
  psx[tc * NN + i] = sx; psy[tc * NN + i] = sy; pse[tc * NN + i] = se;
}

// ---------------- K0b: finalize featn / sev / impacted count ----------------
__global__ void k_prep_b(const float* __restrict__ psx, const float* __restrict__ psy,
    const float* __restrict__ pse, float2* __restrict__ featn,
    float* __restrict__ sev, int* __restrict__ cnt) {
  int i = blockIdx.x * 256 + threadIdx.x;
  float sx = 0.f, sy = 0.f, se = 0.f;
#pragma unroll
  for (int t = 0; t < 8; ++t) {
    sx += psx[t * NN + i]; sy += psy[t * NN + i]; se += pse[t * NN + i];
  }
  sx *= (1.f / 192.f); sy *= (1.f / 192.f); se *= (1.f / 192.f);
  float nrm = sqrtf(sx * sx + sy * sy) + EPSF;
  featn[i] = make_float2(sx / nrm, sy / nrm);
  sev[i] = se;
  unsigned long long m = __ballot(se > 0.f);
  if ((threadIdx.x & 63) == 0) atomicAdd(cnt, (int)__popcll(m));
}

// ---------------- K1: rank-10 adaptive logits -> exp(relu(.)) (streamed) ----------------
__global__ __launch_bounds__(256) void k_gemm(const float* __restrict__ nv1,
    const float* __restrict__ nv2, float* __restrict__ aexp) {
  int j = blockIdx.x * 256 + threadIdx.x;
  int i0 = blockIdx.y * 64;
  float w[10];
#pragma unroll
  for (int d = 0; d < 10; ++d) w[d] = nv2[d * NN + j];
#pragma unroll 4
  for (int it = 0; it < 64; ++it) {
    int i = i0 + it;
    const float* r = nv1 + (size_t)i * 10;  // uniform -> scalar loads
    float a = r[0] * w[0] + r[1] * w[1] + r[2] * w[2] + r[3] * w[3] + r[4] * w[4] +
              r[5] * w[5] + r[6] * w[6] + r[7] * w[7] + r[8] * w[8] + r[9] * w[9];
    aexp[(size_t)i * NN + j] = __expf(fmaxf(a, 0.f));
  }
}

// ---------------- block-wide exact fallback select (rare) ----------------
__device__ void fb_row(int i, const float (&v)[16], int* kidx, float* kval,
                       float* dinv, volatile float* redf, volatile int* redi,
                       int* eq_js, int* eq_cnt, int* slot) {
  const int tid = threadIdx.x;
  const int lane = tid & 63, wv = tid >> 6;
  unsigned cur = 0;
  for (int bit = 30; bit >= 0; --bit) {
    float tf = __uint_as_float(cur | (1u << bit));
    int lc = 0;
#pragma unroll
    for (int c = 0; c < 16; ++c) lc += (v[c] >= tf) ? 1 : 0;
#pragma unroll
    for (int o = 1; o < 64; o <<= 1) lc += __shfl_xor(lc, o, 64);
    __syncthreads();
    if (lane == 0) redi[wv] = lc;
    __syncthreads();
    int tot = redi[0] + redi[1] + redi[2] + redi[3];
    if (tot >= KTOP) cur |= (1u << bit);
  }
  float T = __uint_as_float(cur);
  int lgt = 0;
#pragma unroll
  for (int c = 0; c < 16; ++c) lgt += (v[c] > T) ? 1 : 0;
#pragma unroll
  for (int o = 1; o < 64; o <<= 1) lgt += __shfl_xor(lgt, o, 64);
  __syncthreads();
  if (lane == 0) redi[wv] = lgt;
  if (tid == 0) *eq_cnt = 0;
  __syncthreads();
  int cgt = redi[0] + redi[1] + redi[2] + redi[3];

  float lsum = 0.f;
#pragma unroll
  for (int c = 0; c < 16; ++c) {
    if (v[c] > T) {
      int p = atomicAdd(slot, 1);
      kidx[i * KTOP + p] = c * 256 + tid;
      kval[i * KTOP + p] = v[c];
      lsum += v[c];
    } else if (v[c] == T) {
      int p = atomicAdd(eq_cnt, 1);
      if (p < 64) eq_js[p] = c * 256 + tid;
    }
  }
  __syncthreads();
  int need = KTOP - cgt;
  if (tid == 0) {
    int m = *eq_cnt < 64 ? *eq_cnt : 64;
    for (int s = 0; s < need; ++s) {
      int best = s;
      for (int u = s + 1; u < m; ++u)
        if (eq_js[u] < eq_js[best]) best = u;
      int tmp = eq_js[s]; eq_js[s] = eq_js[best]; eq_js[best] = tmp;
      kidx[i * KTOP + cgt + s] = eq_js[s];
      kval[i * KTOP + cgt + s] = T;
    }
  }
  float tot = block_rsumf(lsum, redf);
  if (tid == 0) dinv[i] = 1.f / sqrtf(tot + (float)need * T + 1.f + EPSF);
}

// ---------------- K2: lean per-row fuse + exact top-k ----------------
__global__ __launch_bounds__(256) void k_row(
    const float* __restrict__ base_adj, const float* __restrict__ aexp,
    const float2* __restrict__ featn, const float* __restrict__ sev,
    const float* __restrict__ alpha, const int* __restrict__ cnt,
    int* __restrict__ kidx, float* __restrict__ kval, float* __restrict__ dinv) {
  const int i = blockIdx.x;
  const int tid = threadIdx.x;
  const int lane = tid & 63, wv = tid >> 6;

  __shared__ float maxima[256];
  __shared__ float candV[64];
  __shared__ int candJ[64];
  __shared__ float redf[12];
  __shared__ int redi[4];
  __shared__ int eq_js[64];
  __shared__ int ccnt, wslot, eq_cnt;
  __shared__ float sTT;

  float2 fi = featn[i];
  float esc = sev[i] * 0.6065306597f;  // sev_i * exp(-0.5)
  float gamma = 1.f / (1.f + __expf(-alpha[0]));

  // ---- pass 1: load b, aexp; sums hs, as, ed ----
  float b[16], ae[16];
  float hs = 0.f, as = 0.f, ed = 0.f;
#pragma unroll
  for (int c = 0; c < 16; ++c) {
    int j = c * 256 + tid;
    float bb = base_adj[(size_t)i * NN + j];
    float av = aexp[(size_t)i * NN + j];
    float2 fj = featn[j];
    b[c] = bb; ae[c] = av;
    hs += __expf(fmaxf(fi.x * fj.x + fi.y * fj.y, 0.f));
    as += av;
    if (esc > 0.f && bb > 0.f) ed += __expf(esc * bb) - 1.f;
  }
  // fused 3-sum block reduction
#pragma unroll
  for (int o = 1; o < 64; o <<= 1) {
    hs += __shfl_xor(hs, o, 64);
    as += __shfl_xor(as, o, 64);
    ed += __shfl_xor(ed, o, 64);
  }
  if (lane == 0) { redf[wv * 3] = hs; redf[wv * 3 + 1] = as; redf[wv * 3 + 2] = ed; }
  __syncthreads();
  float HS = redf[0] + redf[3] + redf[6] + redf[9];
  float AS = redf[1] + redf[4] + redf[7] + redf[10];
  float ES = 4096.f + redf[2] + redf[5] + redf[8] + redf[11];

  float eflag = (*cnt > 0) ? 1.f : 0.f;
  float wh = 0.5f * gamma / HS;
  float we = 0.5f * (1.f - gamma) * eflag / ES;
  float wa = 0.5f / AS;

  // ---- pass 2: v values + thread max (recompute he; featn is L1-hot) ----
  float v[16];
  float m = 0.f;
#pragma unroll
  for (int c = 0; c < 16; ++c) {
    int j = c * 256 + tid;
    float2 fj = featn[j];
    float he = __expf(fmaxf(fi.x * fj.x + fi.y * fj.y, 0.f));
    float val = wh * he + wa * ae[c] + we;
    if (b[c] > 0.f) {
      float add = 0.5f * b[c];
      if (esc > 0.f) add += we * (__expf(esc * b[c]) - 1.f);
      val += add;
    }
    v[c] = val;
    m = fmaxf(m, val);
  }
  maxima[tid] = m;
  if (tid == 0) { ccnt = 0; wslot = 0; }
  __syncthreads();

  // ---- threshold from 256 thread-maxima (12-bit prefix search, wave 0) ----
  if (wv == 0) {
    float x0 = maxima[lane], x1 = maxima[lane + 64];
    float x2 = maxima[lane + 128], x3 = maxima[lane + 192];
    unsigned cur = 0;
    for (int bit = 30; bit >= 19; --bit) {
      float tf = __uint_as_float(cur | (1u << bit));
      int c_ = __popcll(__ballot(x0 >= tf)) + __popcll(__ballot(x1 >= tf)) +
               __popcll(__ballot(x2 >= tf)) + __popcll(__ballot(x3 >= tf));
      if (c_ >= KTOP) cur |= (1u << bit);
    }
    sTT = __uint_as_float(cur);
  }
  __syncthreads();
  float T0 = sTT;

  // ---- collect candidates ----
#pragma unroll
  for (int c = 0; c < 16; ++c) {
    if (v[c] >= T0) {
      int p = atomicAdd(&ccnt, 1);
      if (p < 64) { candV[p] = v[c]; candJ[p] = c * 256 + tid; }
    }
  }
  __syncthreads();
  bool fb = (ccnt > 64);

  // ---- wave-local exact top-20 among candidates ----
  if (!fb && wv == 0) {
    int n = ccnt;
    float lv = (lane < n) ? candV[lane] : 0.f;
    int lj = (lane < n) ? candJ[lane] : 0x7FFFFFFF;
    unsigned cur = 0;
    for (int bit = 30; bit >= 0; --bit) {
      float tf = __uint_as_float(cur | (1u << bit));
      if (__popcll(__ballot(lv >= tf)) >= KTOP) cur |= (1u << bit);
    }
    float T = __uint_as_float(cur);
    bool gt = lv > T;
    int cgt = __popcll(__ballot(gt));
    if (gt) {
      int p = atomicAdd(&wslot, 1);
      kidx[i * KTOP + p] = lj;
      kval[i * KTOP + p] = lv;
    }
    int need = KTOP - cgt;
    bool eq = (lv == T);
    for (int k = 0; k < need; ++k) {
      int pj = eq ? lj : 0x7FFFFFFF;
#pragma unroll
      for (int o = 1; o < 64; o <<= 1) {
        int q = __shfl_xor(pj, o, 64);
        pj = q < pj ? q : pj;
      }
      if (lane == 0) {
        kidx[i * KTOP + cgt + k] = pj;
        kval[i * KTOP + cgt + k] = T;
      }
      if (lj == pj) eq = false;
    }
    float ds = gt ? lv : 0.f;
#pragma unroll
    for (int o = 1; o < 64; o <<= 1) ds += __shfl_xor(ds, o, 64);
    if (lane == 0) dinv[i] = 1.f / sqrtf(ds + (float)need * T + 1.f + EPSF);
  }

  // ---- rare fallback ----
  if (fb) {
    __syncthreads();
    fb_row(i, v, kidx, kval, dinv, redf, redi, eq_js, &eq_cnt, &wslot);
  }
}

// ---------------- K3: scatter top-k + diagonal into zeroed output ----------------
__global__ __launch_bounds__(256) void k_scatter(const int* __restrict__ kidx,
    const float* __restrict__ kval, const float* __restrict__ dinv,
    float* __restrict__ out) {
  int t = blockIdx.x * 256 + threadIdx.x;
  int r = t / 21, s = t - r * 21;
  float di = dinv[r];
  if (s < KTOP) {
    int j = kidx[r * KTOP + s];
    float vv = kval[r * KTOP + s];
    if (j == r) vv += 1.f;
    out[(size_t)r * NN + j] = di * vv * dinv[j];
  } else {
    bool present = false;
#pragma unroll
    for (int k = 0; k < KTOP; ++k) present = present || (kidx[r * KTOP + k] == r);
    if (!present) out[(size_t)r * NN + r] = di * di;
  }
}

extern "C" void kernel_launch(void* const* d_in, const int* in_sizes, int n_in,
                              void* d_out, int out_size, void* d_ws, size_t ws_size,
                              hipStream_t stream) {
  const float* xh    = (const float*)d_in[0];
  const float* ev    = (const float*)d_in[1];
  const float* base  = (const float*)d_in[2];
  const float* nv1   = (const float*)d_in[3];
  const float* nv2   = (const float*)d_in[4];
  const float* alpha = (const float*)d_in[5];
  float* out = (float*)d_out;

  char* ws = (char*)d_ws;
  int*    cnt   = (int*)ws;                 // 4 B (pad 256)
  float2* featn = (float2*)(ws + 256);      // 32 KB
  float*  sev   = (float*)(ws + 33024);     // 16 KB
  float*  dinv  = (float*)(ws + 49408);     // 16 KB
  int*    kidx  = (int*)(ws + 65792);       // 320 KB
  float*  kval  = (float*)(ws + 393472);    // 320 KB
  float*  psx   = (float*)(ws + 721152);    // 128 KB
  float*  psy   = (float*)(ws + 852224);    // 128 KB
  float*  pse   = (float*)(ws + 983296);    // 128 KB

  hipMemsetAsync(cnt, 0, 4, stream);
  k_prep_a<<<128, 256, 0, stream>>>(xh, ev, psx, psy, pse);
  k_prep_b<<<16, 256, 0, stream>>>(psx, psy, pse, featn, sev, cnt);
  // d_out doubles as 64MB aexp scratch until the memset below
  k_gemm<<<dim3(16, 64), 256, 0, stream>>>(nv1, nv2, out);
  k_row<<<NN, 256, 0, stream>>>(base, out, featn, sev, alpha, cnt, kidx, kval, dinv);
  hipMemsetAsync(out, 0, (size_t)NN * NN * sizeof(float), stream);
  k_scatter<<<336, 256, 0, stream>>>(kidx, kval, dinv, out);
}